// Round 3
// baseline (268.288 us; speedup 1.0000x reference)
//
#include <hip/hip_runtime.h>
#include <hip/hip_bf16.h>
#include <cstdint>

// Problem constants
#define T_   4
#define B_   32
#define C_   384
#define HID  1536
#define P_   196          // 14*14
#define MTOT 25088        // T_*B_*P_  (= 196 tiles of 128)

using f32x4  = __attribute__((ext_vector_type(4))) float;
using bf16x8 = __attribute__((ext_vector_type(8))) __bf16;

static __device__ __forceinline__ unsigned short f32_to_bf16(float f) {
  unsigned int u = __builtin_bit_cast(unsigned int, f);
  unsigned int r = (u + 0x7FFFu + ((u >> 16) & 1u)) >> 16;  // RNE
  return (unsigned short)r;
}
static __device__ __forceinline__ float bf16_to_f32(unsigned short h) {
  return __builtin_bit_cast(float, ((unsigned int)h) << 16);
}

static __device__ __forceinline__ f32x4 mfma16x16x32(bf16x8 a, bf16x8 b, f32x4 c) {
  return __builtin_amdgcn_mfma_f32_16x16x32_bf16(a, b, c, 0, 0, 0);
}

#define GLDS(src, dst)                                                              \
  __builtin_amdgcn_global_load_lds((const __attribute__((address_space(1))) void*)(src), \
                                   (__attribute__((address_space(3))) void*)(dst), 16, 0, 0)

// Pipeline sync primitives (counted vmcnt: never drain to 0 mid-loop — T4).
#define VMW(N)  asm volatile("s_waitcnt vmcnt(" #N ")" ::: "memory")
#define LG0     asm volatile("s_waitcnt lgkmcnt(0)" ::: "memory")
#define BARRIER asm volatile("s_barrier" ::: "memory")

// ---------------- prep: split fp32 weights into bf16 hi+lo ----------------
__global__ __launch_bounds__(256) void prep_w(const float* __restrict__ w1, const float* __restrict__ w2,
                                              unsigned short* __restrict__ w1h, unsigned short* __restrict__ w1l,
                                              unsigned short* __restrict__ w2h, unsigned short* __restrict__ w2l) {
  int i = blockIdx.x * 256 + threadIdx.x;
  if (i >= C_ * HID) return;
  float a = w1[i];
  unsigned short h = f32_to_bf16(a);
  w1h[i] = h;
  w1l[i] = f32_to_bf16(a - bf16_to_f32(h));
  float b = w2[i];
  unsigned short h2 = f32_to_bf16(b);
  w2h[i] = h2;
  w2l[i] = f32_to_bf16(b - bf16_to_f32(h2));
}

// ---------------- PLIF on x + transpose to s1t[(b*196+p)*4 + t][c] (bf16 spikes) ----------------
__global__ __launch_bounds__(256) void plif1_t(const float* __restrict__ x, const float* __restrict__ pw1,
                                               unsigned short* __restrict__ s1t) {
  __shared__ float xt[64][65];  // +1 pad: conflict-free transpose
  int b = blockIdx.x, c0 = blockIdx.y * 64, p0 = blockIdx.z * 64;
  int tid  = threadIdx.x;
  int c    = tid & 63;
  int prow = tid >> 6;
  float d1 = 1.0f / (1.0f + expf(-pw1[0]));
  float v[16];
#pragma unroll
  for (int k = 0; k < 16; ++k) v[k] = 0.0f;

  for (int t = 0; t < 4; ++t) {
    __syncthreads();
#pragma unroll
    for (int i = 0; i < 16; ++i) {
      int l = tid + i * 256;
      int cl = l >> 6, pl = l & 63;
      if (p0 + pl < P_)
        xt[cl][pl] = x[(size_t)((t * B_ + b) * C_ + c0 + cl) * P_ + p0 + pl];
    }
    __syncthreads();
#pragma unroll
    for (int k = 0; k < 16; ++k) {
      int p = prow + 4 * k;  // 0..63
      if (p0 + p < P_) {
        float xv = xt[c][p];
        float H  = v[k] + (xv - v[k]) * d1;        // same expr as reference
        bool  s  = (H - 1.0f) >= 0.0f;             // ATan surrogate fwd = heaviside
        s1t[(size_t)((b * P_ + p0 + p) * 4 + t) * C_ + c0 + c] = s ? (unsigned short)0x3F80 : (unsigned short)0;
        v[k] = s ? 0.0f : H;                        // hard reset to 0
      }
    }
  }
}

// ---------------- GEMM1 (s1t[M,K=384] x w1[N=1536,K]) fused with PLIF2 -> s2 spikes bf16 ----------------
// BM=128, BN=128, BK=32, 3-buffer counted-vmcnt pipeline. LDS 72KB -> 2 blocks/CU.
// LDS layout chunk-major: slot(c,r) = c*128 + r holds rows' 16B k-chunk c -> conflict-free b128 reads.
__global__ __launch_bounds__(256) void gemm1_plif2(const unsigned short* __restrict__ s1t,
                                                   const unsigned short* __restrict__ w1h,
                                                   const unsigned short* __restrict__ w1l,
                                                   const float* __restrict__ b1, const float* __restrict__ pw2,
                                                   unsigned short* __restrict__ s2) {
  __shared__ unsigned short As[3 * 4096];
  __shared__ unsigned short Bhs[3 * 4096];
  __shared__ unsigned short Bls[3 * 4096];
  int tid = threadIdx.x;
  int lane = tid & 63, wave = tid >> 6;
  int wm = wave >> 1, wn = wave & 1;
  // XCD-chunked bijective swizzle: 2352 = 8 * 294
  int gid = blockIdx.x;
  int xcd = gid & 7, pos = gid >> 3;
  int lin = xcd * 294 + pos;
  int bx = lin / 12, by = lin - bx * 12;
  int m0 = bx * 128, n0 = by * 128;

  f32x4 acc[4][4];
#pragma unroll
  for (int m = 0; m < 4; ++m)
#pragma unroll
    for (int n = 0; n < 4; ++n) acc[m][n] = (f32x4)0.0f;

  // fragment LDS bases (in shorts): slot = (lane>>4)*128 + row; +m*16 slots = +128 shorts
  const int aBase = ((lane >> 4) * 128 + wm * 64 + (lane & 15)) * 8;
  const int bBase = ((lane >> 4) * 128 + wn * 64 + (lane & 15)) * 8;

  // Each wave stages chunk c=wave, rowblks j=0,1 for A, Bh, Bl (6 GLDS/wave/tile).
#define G1_STAGE(bi, kt) do { int _k0 = (kt) * 32;                                     \
    _Pragma("unroll") for (int _j = 0; _j < 2; ++_j) {                                 \
      GLDS(s1t + (size_t)(m0 + _j * 64 + lane) * C_ + _k0 + wave * 8,                  \
           As  + (bi) * 4096 + wave * 1024 + _j * 512);                                \
      GLDS(w1h + (size_t)(n0 + _j * 64 + lane) * C_ + _k0 + wave * 8,                  \
           Bhs + (bi) * 4096 + wave * 1024 + _j * 512);                                \
      GLDS(w1l + (size_t)(n0 + _j * 64 + lane) * C_ + _k0 + wave * 8,                  \
           Bls + (bi) * 4096 + wave * 1024 + _j * 512);                                \
    } } while (0)

#define G1_BODY(bi) do {                                                               \
    bf16x8 a[4], bh[4], bl[4];                                                         \
    _Pragma("unroll") for (int m = 0; m < 4; ++m)                                      \
      a[m] = *(const bf16x8*)(As + (bi) * 4096 + aBase + m * 128);                     \
    _Pragma("unroll") for (int n = 0; n < 4; ++n) {                                    \
      bh[n] = *(const bf16x8*)(Bhs + (bi) * 4096 + bBase + n * 128);                   \
      bl[n] = *(const bf16x8*)(Bls + (bi) * 4096 + bBase + n * 128);                   \
    }                                                                                  \
    LG0; BARRIER;                                                                      \
    __builtin_amdgcn_s_setprio(1);                                                     \
    _Pragma("unroll") for (int m = 0; m < 4; ++m)                                      \
      _Pragma("unroll") for (int n = 0; n < 4; ++n) {                                  \
        acc[m][n] = mfma16x16x32(a[m], bh[n], acc[m][n]);                              \
        acc[m][n] = mfma16x16x32(a[m], bl[n], acc[m][n]);                              \
      }                                                                                \
    __builtin_amdgcn_s_setprio(0);                                                     \
  } while (0)

  G1_STAGE(0, 0);
  G1_STAGE(1, 1);
  int bc = 0, bs = 2;
  for (int t = 0; t < 10; ++t) {     // NT = 12; stage t+2
    G1_STAGE(bs, t + 2); bs = (bs == 2) ? 0 : bs + 1;
    VMW(12);                          // leave t+1, t+2 in flight (6 GLDS each)
    BARRIER;
    G1_BODY(bc); bc = (bc == 2) ? 0 : bc + 1;
  }
  VMW(6);  BARRIER; G1_BODY(bc); bc = (bc == 2) ? 0 : bc + 1;
  VMW(0);  BARRIER; G1_BODY(bc);
#undef G1_STAGE
#undef G1_BODY

  // Epilogue: rows are (pixel*4 + t); each lane's 4 acc regs = t=0..3 of one pixel -> PLIF2 in registers.
  float d2 = 1.0f / (1.0f + expf(-pw2[0]));
#pragma unroll
  for (int n = 0; n < 4; ++n) {
    int colg = n0 + wn * 64 + n * 16 + (lane & 15);
    float bias = b1[colg];
#pragma unroll
    for (int m = 0; m < 4; ++m) {
      int rowbase = m0 + wm * 64 + m * 16 + ((lane >> 4) << 2);
      float v = 0.0f;
#pragma unroll
      for (int i = 0; i < 4; ++i) {  // i == t
        float xv = acc[m][n][i] + bias;
        float H  = v + (xv - v) * d2;
        bool  s  = (H - 1.0f) >= 0.0f;
        s2[(size_t)(rowbase + i) * HID + colg] = s ? (unsigned short)0x3F80 : (unsigned short)0;
        v = s ? 0.0f : H;
      }
    }
  }
}

// ---------------- GEMM2 (s2[M,K=1536] x w2[N=384,K]) + bias, scatter to channels-first out ----------------
// BM=128, BN=64, BK=32, 3-buffer counted-vmcnt pipeline. LDS 48KB -> 3 blocks/CU.
__global__ __launch_bounds__(256) void gemm2_out(const unsigned short* __restrict__ s2,
                                                 const unsigned short* __restrict__ w2h,
                                                 const unsigned short* __restrict__ w2l,
                                                 const float* __restrict__ b2, float* __restrict__ out) {
  __shared__ unsigned short As[3 * 4096];
  __shared__ unsigned short Bhs[3 * 2048];
  __shared__ unsigned short Bls[3 * 2048];
  int tid = threadIdx.x;
  int lane = tid & 63, wave = tid >> 6;
  int wm = wave >> 1, wn = wave & 1;  // wm: 2x64 rows, wn: 2x32 cols
  // XCD-chunked bijective swizzle: 1176 = 8 * 147
  int gid = blockIdx.x;
  int xcd = gid & 7, pos = gid >> 3;
  int lin = xcd * 147 + pos;
  int bx = lin / 6, by = lin - bx * 6;
  int m0 = bx * 128, n0 = by * 64;

  f32x4 acc[4][2];
#pragma unroll
  for (int m = 0; m < 4; ++m)
#pragma unroll
    for (int n = 0; n < 2; ++n) acc[m][n] = (f32x4)0.0f;

  const int aBase = ((lane >> 4) * 128 + wm * 64 + (lane & 15)) * 8;
  const int bBase = ((lane >> 4) * 64 + wn * 32 + (lane & 15)) * 8;  // B NROWS=64

  // Per wave: A chunk=wave rowblks 0,1 (2 GLDS); Bh chunk=wave (1); Bl chunk=wave (1) -> 4/wave/tile.
#define G2_STAGE(bi, kt) do { int _k0 = (kt) * 32;                                     \
    _Pragma("unroll") for (int _j = 0; _j < 2; ++_j)                                   \
      GLDS(s2 + (size_t)(m0 + _j * 64 + lane) * HID + _k0 + wave * 8,                  \
           As + (bi) * 4096 + wave * 1024 + _j * 512);                                 \
    GLDS(w2h + (size_t)(n0 + lane) * HID + _k0 + wave * 8,                             \
         Bhs + (bi) * 2048 + wave * 512);                                              \
    GLDS(w2l + (size_t)(n0 + lane) * HID + _k0 + wave * 8,                             \
         Bls + (bi) * 2048 + wave * 512);                                              \
  } while (0)

#define G2_BODY(bi) do {                                                               \
    bf16x8 a[4], bh[2], bl[2];                                                         \
    _Pragma("unroll") for (int m = 0; m < 4; ++m)                                      \
      a[m] = *(const bf16x8*)(As + (bi) * 4096 + aBase + m * 128);                     \
    _Pragma("unroll") for (int n = 0; n < 2; ++n) {                                    \
      bh[n] = *(const bf16x8*)(Bhs + (bi) * 2048 + bBase + n * 128);                   \
      bl[n] = *(const bf16x8*)(Bls + (bi) * 2048 + bBase + n * 128);                   \
    }                                                                                  \
    LG0; BARRIER;                                                                      \
    __builtin_amdgcn_s_setprio(1);                                                     \
    _Pragma("unroll") for (int m = 0; m < 4; ++m)                                      \
      _Pragma("unroll") for (int n = 0; n < 2; ++n) {                                  \
        acc[m][n] = mfma16x16x32(a[m], bh[n], acc[m][n]);                              \
        acc[m][n] = mfma16x16x32(a[m], bl[n], acc[m][n]);                              \
      }                                                                                \
    __builtin_amdgcn_s_setprio(0);                                                     \
  } while (0)

  G2_STAGE(0, 0);
  G2_STAGE(1, 1);
  int bc = 0, bs = 2;
  for (int t = 0; t < 46; ++t) {     // NT = 48; stage t+2
    G2_STAGE(bs, t + 2); bs = (bs == 2) ? 0 : bs + 1;
    VMW(8);                           // leave t+1, t+2 in flight (4 GLDS each)
    BARRIER;
    G2_BODY(bc); bc = (bc == 2) ? 0 : bc + 1;
  }
  VMW(4);  BARRIER; G2_BODY(bc); bc = (bc == 2) ? 0 : bc + 1;
  VMW(0);  BARRIER; G2_BODY(bc);
#undef G2_STAGE
#undef G2_BODY

  // Epilogue: bias + scatter to out[t][b][o2][p] (channels-first).
#pragma unroll
  for (int n = 0; n < 2; ++n) {
    int colg = n0 + wn * 32 + n * 16 + (lane & 15);
    float bias = b2[colg];
#pragma unroll
    for (int m = 0; m < 4; ++m) {
      int rowbase = m0 + wm * 64 + m * 16 + ((lane >> 4) << 2);
      int pix = rowbase >> 2;       // = b*196 + p   (t = i)
      int bb  = pix / P_;
      int p   = pix - bb * P_;
#pragma unroll
      for (int i = 0; i < 4; ++i) {
        out[(size_t)((i * B_ + bb) * C_ + colg) * P_ + p] = acc[m][n][i] + bias;
      }
    }
  }
}

// ---------------- launcher ----------------
extern "C" void kernel_launch(void* const* d_in, const int* in_sizes, int n_in,
                              void* d_out, int out_size, void* d_ws, size_t ws_size,
                              hipStream_t stream) {
  const float* x   = (const float*)d_in[0];
  const float* pw1 = (const float*)d_in[1];
  const float* w1  = (const float*)d_in[2];
  const float* b1  = (const float*)d_in[3];
  const float* pw2 = (const float*)d_in[4];
  const float* w2  = (const float*)d_in[5];
  const float* b2  = (const float*)d_in[6];
  float* out = (float*)d_out;

  char* ws = (char*)d_ws;
  unsigned short* s1t = (unsigned short*)(ws);
  unsigned short* s2  = (unsigned short*)(ws + 19267584);
  unsigned short* w1h = (unsigned short*)(ws + 19267584 + 77070336);
  unsigned short* w1l = w1h + 589824;
  unsigned short* w2h = w1l + 589824;
  unsigned short* w2l = w2h + 589824;
  (void)in_sizes; (void)n_in; (void)out_size; (void)ws_size;

  prep_w<<<(C_ * HID + 255) / 256, 256, 0, stream>>>(w1, w2, w1h, w1l, w2h, w2l);
  plif1_t<<<dim3(B_, C_ / 64, 4), 256, 0, stream>>>(x, pw1, s1t);
  gemm1_plif2<<<dim3(MTOT / 128 * (HID / 128)), 256, 0, stream>>>(s1t, w1h, w1l, b1, pw2, s2);
  gemm2_out<<<dim3(MTOT / 128 * (C_ / 64)), 256, 0, stream>>>(s2, w2h, w2l, b2, out);
}

// Round 5
// 195.994 us; speedup vs baseline: 1.3689x; 1.3689x over previous
//
#include <hip/hip_runtime.h>
#include <hip/hip_bf16.h>
#include <cstdint>

// Problem constants
#define T_   4
#define B_   32
#define C_   384
#define HID  1536
#define P_   196          // 14*14
#define MTOT 25088        // T_*B_*P_

using f32x4  = __attribute__((ext_vector_type(4))) float;
using bf16x8 = __attribute__((ext_vector_type(8))) __bf16;

static __device__ __forceinline__ unsigned short f32_to_bf16(float f) {
  unsigned int u = __builtin_bit_cast(unsigned int, f);
  unsigned int r = (u + 0x7FFFu + ((u >> 16) & 1u)) >> 16;  // RNE
  return (unsigned short)r;
}
static __device__ __forceinline__ float bf16_to_f32(unsigned short h) {
  return __builtin_bit_cast(float, ((unsigned int)h) << 16);
}

static __device__ __forceinline__ f32x4 mfma16x16x32(bf16x8 a, bf16x8 b, f32x4 c) {
  return __builtin_amdgcn_mfma_f32_16x16x32_bf16(a, b, c, 0, 0, 0);
}

#define GLDS(src, dst)                                                              \
  __builtin_amdgcn_global_load_lds((const __attribute__((address_space(1))) void*)(src), \
                                   (__attribute__((address_space(3))) void*)(dst), 16, 0, 0)

#define VMW2 asm volatile("s_waitcnt vmcnt(2)" ::: "memory")
#define VMW6 asm volatile("s_waitcnt vmcnt(6)" ::: "memory")
#define VMW0 asm volatile("s_waitcnt vmcnt(0)" ::: "memory")
#define LG0  asm volatile("s_waitcnt lgkmcnt(0)" ::: "memory")
#define BAR  __builtin_amdgcn_s_barrier()
#define NOP  ((void)0)

// ---------------- prep: split fp32 weights into bf16 hi+lo ----------------
__global__ __launch_bounds__(256) void prep_w(const float* __restrict__ w1, const float* __restrict__ w2,
                                              unsigned short* __restrict__ w1h, unsigned short* __restrict__ w1l,
                                              unsigned short* __restrict__ w2h, unsigned short* __restrict__ w2l) {
  int i = blockIdx.x * 256 + threadIdx.x;
  if (i >= C_ * HID) return;
  float a = w1[i];
  unsigned short h = f32_to_bf16(a);
  w1h[i] = h;
  w1l[i] = f32_to_bf16(a - bf16_to_f32(h));
  float b = w2[i];
  unsigned short h2 = f32_to_bf16(b);
  w2h[i] = h2;
  w2l[i] = f32_to_bf16(b - bf16_to_f32(h2));
}

// ---------------- PLIF on x + transpose to s1t[(b*196+p)*4 + t][c] (bf16 spikes) ----------------
__global__ __launch_bounds__(256) void plif1_t(const float* __restrict__ x, const float* __restrict__ pw1,
                                               unsigned short* __restrict__ s1t) {
  __shared__ float xt[64][65];  // +1 pad: conflict-free transpose
  int b = blockIdx.x, c0 = blockIdx.y * 64, p0 = blockIdx.z * 64;
  int tid  = threadIdx.x;
  int c    = tid & 63;
  int prow = tid >> 6;
  float d1 = 1.0f / (1.0f + expf(-pw1[0]));
  float v[16];
#pragma unroll
  for (int k = 0; k < 16; ++k) v[k] = 0.0f;

  for (int t = 0; t < 4; ++t) {
    __syncthreads();
#pragma unroll
    for (int i = 0; i < 16; ++i) {
      int l = tid + i * 256;
      int cl = l >> 6, pl = l & 63;
      if (p0 + pl < P_)
        xt[cl][pl] = x[(size_t)((t * B_ + b) * C_ + c0 + cl) * P_ + p0 + pl];
    }
    __syncthreads();
#pragma unroll
    for (int k = 0; k < 16; ++k) {
      int p = prow + 4 * k;  // 0..63
      if (p0 + p < P_) {
        float xv = xt[c][p];
        float H  = v[k] + (xv - v[k]) * d1;        // same expr as reference
        bool  s  = (H - 1.0f) >= 0.0f;             // ATan surrogate fwd = heaviside
        s1t[(size_t)((b * P_ + p0 + p) * 4 + t) * C_ + c0 + c] = s ? (unsigned short)0x3F80 : (unsigned short)0;
        v[k] = s ? 0.0f : H;                        // hard reset to 0
      }
    }
  }
}

// ---------------- GEMM1: BM=256 BN=128 BK=64, 512 thr, 2 LDS buffers, 4 phases/tile ----------------
// Issue groups match read phases: A02 (rows 0-63,128-191; read at mh=0), A13 (64-127,192-255; mh=1),
// BH/BL (read every phase). Waits: vmcnt(2) at p0 (retires A13(t)), vmcnt(2) at p3 (retires BH,BL,A02(t+1)).
__global__ __launch_bounds__(512) void gemm1_plif2(const unsigned short* __restrict__ s1t,
                                                   const unsigned short* __restrict__ w1h,
                                                   const unsigned short* __restrict__ w1l,
                                                   const float* __restrict__ b1, const float* __restrict__ pw2,
                                                   unsigned short* __restrict__ s2) {
  __shared__ unsigned short As[2 * 16384];
  __shared__ unsigned short Bhs[2 * 8192];
  __shared__ unsigned short Bls[2 * 8192];
  int tid = threadIdx.x;
  int lane = tid & 63, wave = tid >> 6;
  int wm = wave >> 2, wn = wave & 3;
  // XCD-chunked bijective swizzle: 1176 = 8 * 147
  int gid = blockIdx.x;
  int xcd = gid & 7, pos = gid >> 3;
  int lin = xcd * 147 + pos;
  int bx = lin / 12, by = lin - bx * 12;
  int m0 = bx * 256, n0 = by * 128;

  f32x4 acc[8][2];
#pragma unroll
  for (int m = 0; m < 8; ++m)
#pragma unroll
    for (int n = 0; n < 2; ++n) acc[m][n] = (f32x4)0.0f;

  // per-thread pre-swizzled source pointers (row = l>>3, kchunk = (l&7)^(row&7))
  const unsigned short *pA0, *pA1, *pA2, *pA3, *pH0, *pH1, *pL0, *pL1;
  {
    int l, row, kb;
    l = tid;        row = l >> 3; kb = (l & 7) ^ (row & 7);
    pA0 = s1t + (size_t)(m0 + row) * C_ + kb * 8;
    pH0 = w1h + (size_t)(n0 + row) * C_ + kb * 8;
    pL0 = w1l + (size_t)(n0 + row) * C_ + kb * 8;
    l = 512 + tid;  row = l >> 3; kb = (l & 7) ^ (row & 7);
    pA1 = s1t + (size_t)(m0 + row) * C_ + kb * 8;
    pH1 = w1h + (size_t)(n0 + row) * C_ + kb * 8;
    pL1 = w1l + (size_t)(n0 + row) * C_ + kb * 8;
    l = 1024 + tid; row = l >> 3; kb = (l & 7) ^ (row & 7);
    pA2 = s1t + (size_t)(m0 + row) * C_ + kb * 8;
    l = 1536 + tid; row = l >> 3; kb = (l & 7) ^ (row & 7);
    pA3 = s1t + (size_t)(m0 + row) * C_ + kb * 8;
  }

#define ISS_A02(bn, kt) do {                                           \
    GLDS(pA0 + (kt) * 64, As + (bn) * 16384 + 0 * 4096 + wave * 512);  \
    GLDS(pA2 + (kt) * 64, As + (bn) * 16384 + 2 * 4096 + wave * 512);  \
  } while (0)
#define ISS_A13(bn, kt) do {                                           \
    GLDS(pA1 + (kt) * 64, As + (bn) * 16384 + 1 * 4096 + wave * 512);  \
    GLDS(pA3 + (kt) * 64, As + (bn) * 16384 + 3 * 4096 + wave * 512);  \
  } while (0)
#define ISS_BH(bn, kt) do {                                            \
    GLDS(pH0 + (kt) * 64, Bhs + (bn) * 8192 + 0 * 4096 + wave * 512);  \
    GLDS(pH1 + (kt) * 64, Bhs + (bn) * 8192 + 1 * 4096 + wave * 512);  \
  } while (0)
#define ISS_BL(bn, kt) do {                                            \
    GLDS(pL0 + (kt) * 64, Bls + (bn) * 8192 + 0 * 4096 + wave * 512);  \
    GLDS(pL1 + (kt) * 64, Bls + (bn) * 8192 + 1 * 4096 + wave * 512);  \
  } while (0)

#define PHASE(bi, mh, ks, ISSUE, WAIT) do {                                        \
    bf16x8 afr[4], bhf[2], blf[2];                                                 \
    const int kof = (ks) * 32 + ((lane >> 4) << 3);                                \
    _Pragma("unroll") for (int j = 0; j < 4; ++j) {                                \
      int row = wm * 128 + ((mh) * 4 + j) * 16 + (lane & 15);                      \
      afr[j] = *(const bf16x8*)(As + (bi) * 16384 + row * 64 + (kof ^ ((row & 7) << 3))); \
    }                                                                              \
    _Pragma("unroll") for (int nn = 0; nn < 2; ++nn) {                             \
      int row = wn * 32 + nn * 16 + (lane & 15);                                   \
      int idx = row * 64 + (kof ^ ((row & 7) << 3));                               \
      bhf[nn] = *(const bf16x8*)(Bhs + (bi) * 8192 + idx);                         \
      blf[nn] = *(const bf16x8*)(Bls + (bi) * 8192 + idx);                         \
    }                                                                              \
    ISSUE;                                                                         \
    WAIT;                                                                          \
    BAR;                                                                           \
    LG0;                                                                           \
    __builtin_amdgcn_sched_barrier(0);                                             \
    __builtin_amdgcn_s_setprio(1);                                                 \
    _Pragma("unroll") for (int j = 0; j < 4; ++j)                                  \
      _Pragma("unroll") for (int nn = 0; nn < 2; ++nn) {                           \
        acc[(mh) * 4 + j][nn] = mfma16x16x32(afr[j], bhf[nn], acc[(mh) * 4 + j][nn]); \
        acc[(mh) * 4 + j][nn] = mfma16x16x32(afr[j], blf[nn], acc[(mh) * 4 + j][nn]); \
      }                                                                            \
    __builtin_amdgcn_s_setprio(0);                                                 \
    BAR;                                                                           \
  } while (0)

  // ---- K loop, NT = 6 ----
  ISS_BH(0, 0); ISS_BL(0, 0); ISS_A02(0, 0); ISS_A13(0, 0);
  VMW2; BAR;                              // retires BH,BL,A02(0); leaves A13(0)
  for (int t = 0; t < 5; ++t) {
    int bi = t & 1, bn = bi ^ 1;
    PHASE(bi, 0, 0, ISS_BH(bn, t + 1), VMW2);   // retires A13(t); leaves BH(t+1)
    PHASE(bi, 1, 0, ISS_BL(bn, t + 1), NOP);
    PHASE(bi, 0, 1, ISS_A02(bn, t + 1), NOP);
    PHASE(bi, 1, 1, ISS_A13(bn, t + 1), VMW2);  // retires BH,BL,A02(t+1); leaves A13(t+1)
  }
  {
    int bi = 5 & 1;
    PHASE(bi, 0, 0, NOP, VMW0);                 // retires A13(5)
    PHASE(bi, 1, 0, NOP, NOP);
    PHASE(bi, 0, 1, NOP, NOP);
    PHASE(bi, 1, 1, NOP, NOP);
  }
#undef ISS_A02
#undef ISS_A13
#undef ISS_BH
#undef ISS_BL
#undef PHASE

  // Epilogue: rows are (pixel*4 + t); each lane's 4 acc regs = t=0..3 of one pixel -> PLIF2 in registers.
  float d2 = 1.0f / (1.0f + expf(-pw2[0]));
#pragma unroll
  for (int n = 0; n < 2; ++n) {
    int colg = n0 + wn * 32 + n * 16 + (lane & 15);
    float bias = b1[colg];
#pragma unroll
    for (int m = 0; m < 8; ++m) {
      int rowbase = m0 + wm * 128 + m * 16 + ((lane >> 4) << 2);
      float v = 0.0f;
#pragma unroll
      for (int i = 0; i < 4; ++i) {  // i == t
        float xv = acc[m][n][i] + bias;
        float H  = v + (xv - v) * d2;
        bool  s  = (H - 1.0f) >= 0.0f;
        s2[(size_t)(rowbase + i) * HID + colg] = s ? (unsigned short)0x3F80 : (unsigned short)0;
        v = s ? 0.0f : H;
      }
    }
  }
}

// ---------------- GEMM2: BM=128 BN=128 BK=64, 512 thr, 3 LDS buffers, 2 phases/tile, lookahead-2 ----------------
// Every phase reads the whole tile -> tile t confirmed by vmcnt(6) at p1(t-1) (leaves exactly tile t+1's 6 loads).
__global__ __launch_bounds__(512) void gemm2_out(const unsigned short* __restrict__ s2,
                                                 const unsigned short* __restrict__ w2h,
                                                 const unsigned short* __restrict__ w2l,
                                                 const float* __restrict__ b2, float* __restrict__ out) {
  __shared__ unsigned short As[3 * 8192];
  __shared__ unsigned short Bhs[3 * 8192];
  __shared__ unsigned short Bls[3 * 8192];
  int tid = threadIdx.x;
  int lane = tid & 63, wave = tid >> 6;
  int wm = wave >> 2, wn = wave & 3;   // 2M x 4N; per-wave 64 rows x 32 cols
  // m204 bijective XCD swizzle: 588 blocks, q=73, r=4
  int gid = blockIdx.x;
  int xcd = gid & 7, pos = gid >> 3;
  int lin = (xcd < 4) ? (xcd * 74 + pos) : (296 + (xcd - 4) * 73 + pos);
  int bx = lin / 3, by = lin - bx * 3;
  int m0 = bx * 128, n0 = by * 128;

  f32x4 acc[4][2];
#pragma unroll
  for (int m = 0; m < 4; ++m)
#pragma unroll
    for (int n = 0; n < 2; ++n) acc[m][n] = (f32x4)0.0f;

  const unsigned short *pA0, *pA1, *pH0, *pH1, *pL0, *pL1;
  {
    int l, row, kb;
    l = tid;        row = l >> 3; kb = (l & 7) ^ (row & 7);
    pA0 = s2  + (size_t)(m0 + row) * HID + kb * 8;
    pH0 = w2h + (size_t)(n0 + row) * HID + kb * 8;
    pL0 = w2l + (size_t)(n0 + row) * HID + kb * 8;
    l = 512 + tid;  row = l >> 3; kb = (l & 7) ^ (row & 7);
    pA1 = s2  + (size_t)(m0 + row) * HID + kb * 8;
    pH1 = w2h + (size_t)(n0 + row) * HID + kb * 8;
    pL1 = w2l + (size_t)(n0 + row) * HID + kb * 8;
  }

#define G2_ISS_A(bn, kt) do {                                          \
    GLDS(pA0 + (kt) * 64, As + (bn) * 8192 + 0 * 4096 + wave * 512);   \
    GLDS(pA1 + (kt) * 64, As + (bn) * 8192 + 1 * 4096 + wave * 512);   \
  } while (0)
#define G2_ISS_B(bn, kt) do {                                          \
    GLDS(pH0 + (kt) * 64, Bhs + (bn) * 8192 + 0 * 4096 + wave * 512);  \
    GLDS(pH1 + (kt) * 64, Bhs + (bn) * 8192 + 1 * 4096 + wave * 512);  \
    GLDS(pL0 + (kt) * 64, Bls + (bn) * 8192 + 0 * 4096 + wave * 512);  \
    GLDS(pL1 + (kt) * 64, Bls + (bn) * 8192 + 1 * 4096 + wave * 512);  \
  } while (0)

#define PH2(bi, ks, ISSUE, WAIT) do {                                              \
    bf16x8 afr[4], bhf[2], blf[2];                                                 \
    const int kof = (ks) * 32 + ((lane >> 4) << 3);                                \
    _Pragma("unroll") for (int j = 0; j < 4; ++j) {                                \
      int row = wm * 64 + j * 16 + (lane & 15);                                    \
      afr[j] = *(const bf16x8*)(As + (bi) * 8192 + row * 64 + (kof ^ ((row & 7) << 3))); \
    }                                                                              \
    _Pragma("unroll") for (int nn = 0; nn < 2; ++nn) {                             \
      int row = wn * 32 + nn * 16 + (lane & 15);                                   \
      int idx = row * 64 + (kof ^ ((row & 7) << 3));                               \
      bhf[nn] = *(const bf16x8*)(Bhs + (bi) * 8192 + idx);                         \
      blf[nn] = *(const bf16x8*)(Bls + (bi) * 8192 + idx);                         \
    }                                                                              \
    ISSUE;                                                                         \
    WAIT;                                                                          \
    BAR;                                                                           \
    LG0;                                                                           \
    __builtin_amdgcn_sched_barrier(0);                                             \
    __builtin_amdgcn_s_setprio(1);                                                 \
    _Pragma("unroll") for (int j = 0; j < 4; ++j)                                  \
      _Pragma("unroll") for (int nn = 0; nn < 2; ++nn) {                           \
        acc[j][nn] = mfma16x16x32(afr[j], bhf[nn], acc[j][nn]);                    \
        acc[j][nn] = mfma16x16x32(afr[j], blf[nn], acc[j][nn]);                    \
      }                                                                            \
    __builtin_amdgcn_s_setprio(0);                                                 \
    BAR;                                                                           \
  } while (0)

  // ---- K loop, NT = 24, 3 buffers, prefetch t+2 ----
  G2_ISS_A(0, 0); G2_ISS_B(0, 0); G2_ISS_A(1, 1); G2_ISS_B(1, 1);
  VMW6; BAR;                                  // retires tile 0 (6 loads); leaves tile 1
  for (int t = 0; t < 22; ++t) {
    int bi = t % 3, b2i = (t + 2) % 3;
    PH2(bi, 0, G2_ISS_A(b2i, t + 2), NOP);
    PH2(bi, 1, G2_ISS_B(b2i, t + 2), VMW6);   // retires tile t+1; leaves tile t+2
  }
  { int bi = 22 % 3; PH2(bi, 0, NOP, NOP); PH2(bi, 1, NOP, VMW0); }
  { int bi = 23 % 3; PH2(bi, 0, NOP, NOP); PH2(bi, 1, NOP, NOP); }
#undef G2_ISS_A
#undef G2_ISS_B
#undef PH2

  // Epilogue: bias + scatter to out[t][b][o2][p] (channels-first).
#pragma unroll
  for (int n = 0; n < 2; ++n) {
    int colg = n0 + wn * 32 + n * 16 + (lane & 15);
    float bias = b2[colg];
#pragma unroll
    for (int m = 0; m < 4; ++m) {
      int rowbase = m0 + wm * 64 + m * 16 + ((lane >> 4) << 2);
      int pix = rowbase >> 2;       // = b*196 + p   (t = i)
      int bb  = pix / P_;
      int p   = pix - bb * P_;
#pragma unroll
      for (int i = 0; i < 4; ++i) {
        out[(size_t)((i * B_ + bb) * C_ + colg) * P_ + p] = acc[m][n][i] + bias;
      }
    }
  }
}

// ---------------- launcher ----------------
extern "C" void kernel_launch(void* const* d_in, const int* in_sizes, int n_in,
                              void* d_out, int out_size, void* d_ws, size_t ws_size,
                              hipStream_t stream) {
  const float* x   = (const float*)d_in[0];
  const float* pw1 = (const float*)d_in[1];
  const float* w1  = (const float*)d_in[2];
  const float* b1  = (const float*)d_in[3];
  const float* pw2 = (const float*)d_in[4];
  const float* w2  = (const float*)d_in[5];
  const float* b2  = (const float*)d_in[6];
  float* out = (float*)d_out;

  char* ws = (char*)d_ws;
  unsigned short* s1t = (unsigned short*)(ws);
  unsigned short* s2  = (unsigned short*)(ws + 19267584);
  unsigned short* w1h = (unsigned short*)(ws + 19267584 + 77070336);
  unsigned short* w1l = w1h + 589824;
  unsigned short* w2h = w1l + 589824;
  unsigned short* w2l = w2h + 589824;
  (void)in_sizes; (void)n_in; (void)out_size; (void)ws_size;

  prep_w<<<(C_ * HID + 255) / 256, 256, 0, stream>>>(w1, w2, w1h, w1l, w2h, w2l);
  plif1_t<<<dim3(B_, C_ / 64, 4), 256, 0, stream>>>(x, pw1, s1t);
  gemm1_plif2<<<dim3((MTOT / 256) * (HID / 128)), 512, 0, stream>>>(s1t, w1h, w1l, b1, pw2, s2);
  gemm2_out<<<dim3((MTOT / 128) * (C_ / 128)), 512, 0, stream>>>(s2, w2h, w2l, b2, out);
}

// Round 6
// 191.965 us; speedup vs baseline: 1.3976x; 1.0210x over previous
//
#include <hip/hip_runtime.h>
#include <hip/hip_bf16.h>
#include <cstdint>

// Problem constants
#define T_   4
#define B_   32
#define C_   384
#define HID  1536
#define P_   196          // 14*14
#define MTOT 25088        // T_*B_*P_

using f32x4  = __attribute__((ext_vector_type(4))) float;
using bf16x8 = __attribute__((ext_vector_type(8))) __bf16;

static __device__ __forceinline__ unsigned short f32_to_bf16(float f) {
  unsigned int u = __builtin_bit_cast(unsigned int, f);
  unsigned int r = (u + 0x7FFFu + ((u >> 16) & 1u)) >> 16;  // RNE
  return (unsigned short)r;
}
static __device__ __forceinline__ float bf16_to_f32(unsigned short h) {
  return __builtin_bit_cast(float, ((unsigned int)h) << 16);
}

static __device__ __forceinline__ f32x4 mfma16x16x32(bf16x8 a, bf16x8 b, f32x4 c) {
  return __builtin_amdgcn_mfma_f32_16x16x32_bf16(a, b, c, 0, 0, 0);
}

#define GLDS(src, dst)                                                              \
  __builtin_amdgcn_global_load_lds((const __attribute__((address_space(1))) void*)(src), \
                                   (__attribute__((address_space(3))) void*)(dst), 16, 0, 0)

#define VMW0 asm volatile("s_waitcnt vmcnt(0)" ::: "memory")
#define LG0  asm volatile("s_waitcnt lgkmcnt(0)" ::: "memory")
#define BAR  __builtin_amdgcn_s_barrier()

// ---------------- prep: split fp32 weights into bf16 hi+lo ----------------
__global__ __launch_bounds__(256) void prep_w(const float* __restrict__ w1, const float* __restrict__ w2,
                                              unsigned short* __restrict__ w1h, unsigned short* __restrict__ w1l,
                                              unsigned short* __restrict__ w2h, unsigned short* __restrict__ w2l) {
  int i = blockIdx.x * 256 + threadIdx.x;
  if (i >= C_ * HID) return;
  float a = w1[i];
  unsigned short h = f32_to_bf16(a);
  w1h[i] = h;
  w1l[i] = f32_to_bf16(a - bf16_to_f32(h));
  float b = w2[i];
  unsigned short h2 = f32_to_bf16(b);
  w2h[i] = h2;
  w2l[i] = f32_to_bf16(b - bf16_to_f32(h2));
}

// ---------------- PLIF on x + transpose to s1t[(b*196+p)*4 + t][c] (bf16 spikes) ----------------
__global__ __launch_bounds__(256) void plif1_t(const float* __restrict__ x, const float* __restrict__ pw1,
                                               unsigned short* __restrict__ s1t) {
  __shared__ float xt[64][65];  // +1 pad: conflict-free transpose
  int b = blockIdx.x, c0 = blockIdx.y * 64, p0 = blockIdx.z * 64;
  int tid  = threadIdx.x;
  int c    = tid & 63;
  int prow = tid >> 6;
  float d1 = 1.0f / (1.0f + expf(-pw1[0]));
  float v[16];
#pragma unroll
  for (int k = 0; k < 16; ++k) v[k] = 0.0f;

  for (int t = 0; t < 4; ++t) {
    __syncthreads();
#pragma unroll
    for (int i = 0; i < 16; ++i) {
      int l = tid + i * 256;
      int cl = l >> 6, pl = l & 63;
      if (p0 + pl < P_)
        xt[cl][pl] = x[(size_t)((t * B_ + b) * C_ + c0 + cl) * P_ + p0 + pl];
    }
    __syncthreads();
#pragma unroll
    for (int k = 0; k < 16; ++k) {
      int p = prow + 4 * k;  // 0..63
      if (p0 + p < P_) {
        float xv = xt[c][p];
        float H  = v[k] + (xv - v[k]) * d1;        // same expr as reference
        bool  s  = (H - 1.0f) >= 0.0f;             // ATan surrogate fwd = heaviside
        s1t[(size_t)((b * P_ + p0 + p) * 4 + t) * C_ + c0 + c] = s ? (unsigned short)0x3F80 : (unsigned short)0;
        v[k] = s ? 0.0f : H;                        // hard reset to 0
      }
    }
  }
}

// ======== Common GEMM geometry: BM=128, BN=64, BK=64, 256 thr (4 waves: 2M x 2N), 2 LDS buffers ========
// 2-phase overlap per tile: STAGE(t+1) issued BEFORE compute(t); single vmcnt(0)+s_barrier per tile.
// LDS 64 KB -> 2 blocks/CU. Chunk-swizzled rows (pre-swizzled global source), conflict-free ds_read_b128.

#define PTR_SETUP(Aptr, Hptr, Lptr, LD)                                             \
  const unsigned short *pA0, *pA1, *pA2, *pA3, *pH0, *pH1, *pL0, *pL1;              \
  {                                                                                 \
    int l, row, kb;                                                                 \
    l = tid;        row = l >> 3; kb = (l & 7) ^ (row & 7);                         \
    pA0 = (Aptr) + (size_t)(m0 + row) * (LD) + kb * 8;                              \
    pH0 = (Hptr) + (size_t)(n0 + row) * (LD) + kb * 8;                              \
    pL0 = (Lptr) + (size_t)(n0 + row) * (LD) + kb * 8;                              \
    l = 256 + tid;  row = l >> 3; kb = (l & 7) ^ (row & 7);                         \
    pA1 = (Aptr) + (size_t)(m0 + row) * (LD) + kb * 8;                              \
    pH1 = (Hptr) + (size_t)(n0 + row) * (LD) + kb * 8;                              \
    pL1 = (Lptr) + (size_t)(n0 + row) * (LD) + kb * 8;                              \
    l = 512 + tid;  row = l >> 3; kb = (l & 7) ^ (row & 7);                         \
    pA2 = (Aptr) + (size_t)(m0 + row) * (LD) + kb * 8;                              \
    l = 768 + tid;  row = l >> 3; kb = (l & 7) ^ (row & 7);                         \
    pA3 = (Aptr) + (size_t)(m0 + row) * (LD) + kb * 8;                              \
  }

#define STAGE(bi, kt) do {                                                          \
    GLDS(pA0 + (kt) * 64, As  + (bi) * 8192 + 0 * 2048 + wave * 512);               \
    GLDS(pA1 + (kt) * 64, As  + (bi) * 8192 + 1 * 2048 + wave * 512);               \
    GLDS(pA2 + (kt) * 64, As  + (bi) * 8192 + 2 * 2048 + wave * 512);               \
    GLDS(pA3 + (kt) * 64, As  + (bi) * 8192 + 3 * 2048 + wave * 512);               \
    GLDS(pH0 + (kt) * 64, Bhs + (bi) * 4096 + 0 * 2048 + wave * 512);               \
    GLDS(pH1 + (kt) * 64, Bhs + (bi) * 4096 + 1 * 2048 + wave * 512);               \
    GLDS(pL0 + (kt) * 64, Bls + (bi) * 4096 + 0 * 2048 + wave * 512);               \
    GLDS(pL1 + (kt) * 64, Bls + (bi) * 4096 + 1 * 2048 + wave * 512);               \
  } while (0)

// Read all 16 fragments (both k-halves), then one lgkmcnt(0), then 32 MFMA.
// Per-acc order: ks0-hi, ks0-lo, ks1-hi, ks1-lo == identical to round-2 math (bitwise).
#define COMPUTE(bi) do {                                                            \
    bf16x8 a[2][4], bh[2][2], bl[2][2];                                             \
    _Pragma("unroll") for (int ks = 0; ks < 2; ++ks) {                              \
      const int kof = ks * 32 + ((lane >> 4) << 3);                                 \
      _Pragma("unroll") for (int m = 0; m < 4; ++m) {                               \
        int row = wm * 64 + m * 16 + (lane & 15);                                   \
        a[ks][m] = *(const bf16x8*)(As + (bi) * 8192 + row * 64 + (kof ^ ((row & 7) << 3))); \
      }                                                                             \
      _Pragma("unroll") for (int n = 0; n < 2; ++n) {                               \
        int row = wn * 32 + n * 16 + (lane & 15);                                   \
        int idx = row * 64 + (kof ^ ((row & 7) << 3));                              \
        bh[ks][n] = *(const bf16x8*)(Bhs + (bi) * 4096 + idx);                      \
        bl[ks][n] = *(const bf16x8*)(Bls + (bi) * 4096 + idx);                      \
      }                                                                             \
    }                                                                               \
    LG0;                                                                            \
    __builtin_amdgcn_sched_barrier(0);                                              \
    __builtin_amdgcn_s_setprio(1);                                                  \
    _Pragma("unroll") for (int ks = 0; ks < 2; ++ks)                                \
      _Pragma("unroll") for (int m = 0; m < 4; ++m)                                 \
        _Pragma("unroll") for (int n = 0; n < 2; ++n) {                             \
          acc[m][n] = mfma16x16x32(a[ks][m], bh[ks][n], acc[m][n]);                 \
          acc[m][n] = mfma16x16x32(a[ks][m], bl[ks][n], acc[m][n]);                 \
        }                                                                           \
    __builtin_amdgcn_s_setprio(0);                                                  \
  } while (0)

// ---------------- GEMM1 (s1t[M,384] x w1[1536,384]^T) fused with PLIF2 -> s2 spikes ----------------
// Grid 196*24 = 4704 = 8*588. Each XCD owns 3 N-panels (294 KB hi+lo, L2-resident) and
// streams A once: L3 traffic ~160 MB vs 921 MB with the old orientation.
__global__ __launch_bounds__(256, 2) void gemm1_plif2(const unsigned short* __restrict__ s1t,
                                                      const unsigned short* __restrict__ w1h,
                                                      const unsigned short* __restrict__ w1l,
                                                      const float* __restrict__ b1, const float* __restrict__ pw2,
                                                      unsigned short* __restrict__ s2) {
  __shared__ unsigned short As[2 * 8192];
  __shared__ unsigned short Bhs[2 * 4096];
  __shared__ unsigned short Bls[2 * 4096];
  int tid = threadIdx.x;
  int lane = tid & 63, wave = tid >> 6;
  int wm = wave >> 1, wn = wave & 1;
  int gid = blockIdx.x;
  int xcd = gid & 7, pos = gid >> 3;       // HW round-robins gid%8 across XCDs
  int bx = pos / 3, bysub = pos - bx * 3;  // A-panel reused 3x back-to-back per XCD
  int by = xcd * 3 + bysub;
  int m0 = bx * 128, n0 = by * 64;

  f32x4 acc[4][2];
#pragma unroll
  for (int m = 0; m < 4; ++m)
#pragma unroll
    for (int n = 0; n < 2; ++n) acc[m][n] = (f32x4)0.0f;

  PTR_SETUP(s1t, w1h, w1l, C_)

  // K loop, NT = 6, tile t lives in buffer t&1.
  STAGE(0, 0);
  VMW0; BAR;
  for (int t = 0; t < 5; ++t) {
    STAGE((t & 1) ^ 1, t + 1);   // issue next tile BEFORE computing current
    COMPUTE(t & 1);
    VMW0; BAR;                   // staged tile confirmed; readers of buf(t&1) done
  }
  COMPUTE(1);                    // tile 5

  // Epilogue: rows are (pixel*4 + t); each lane's 4 acc regs = t=0..3 of one pixel -> PLIF2 in registers.
  float d2 = 1.0f / (1.0f + expf(-pw2[0]));
#pragma unroll
  for (int n = 0; n < 2; ++n) {
    int colg = n0 + wn * 32 + n * 16 + (lane & 15);
    float bias = b1[colg];
#pragma unroll
    for (int m = 0; m < 4; ++m) {
      int rowbase = m0 + wm * 64 + m * 16 + ((lane >> 4) << 2);
      float v = 0.0f;
#pragma unroll
      for (int i = 0; i < 4; ++i) {  // i == t
        float xv = acc[m][n][i] + bias;
        float H  = v + (xv - v) * d2;
        bool  s  = (H - 1.0f) >= 0.0f;
        s2[(size_t)(rowbase + i) * HID + colg] = s ? (unsigned short)0x3F80 : (unsigned short)0;
        v = s ? 0.0f : H;
      }
    }
  }
}

// ---------------- GEMM2 (s2[M,1536] x w2[384,1536]^T) + bias, scatter to channels-first out ----------------
// Grid 196*6 = 1176 = 8*147, by fastest per XCD (w2 hi+lo 2.36 MB L2-resident; A read once).
__global__ __launch_bounds__(256, 2) void gemm2_out(const unsigned short* __restrict__ s2,
                                                    const unsigned short* __restrict__ w2h,
                                                    const unsigned short* __restrict__ w2l,
                                                    const float* __restrict__ b2, float* __restrict__ out) {
  __shared__ unsigned short As[2 * 8192];
  __shared__ unsigned short Bhs[2 * 4096];
  __shared__ unsigned short Bls[2 * 4096];
  int tid = threadIdx.x;
  int lane = tid & 63, wave = tid >> 6;
  int wm = wave >> 1, wn = wave & 1;
  int gid = blockIdx.x;
  int xcd = gid & 7, pos = gid >> 3;
  int lin = xcd * 147 + pos;
  int bx = lin / 6, by = lin - bx * 6;
  int m0 = bx * 128, n0 = by * 64;

  f32x4 acc[4][2];
#pragma unroll
  for (int m = 0; m < 4; ++m)
#pragma unroll
    for (int n = 0; n < 2; ++n) acc[m][n] = (f32x4)0.0f;

  PTR_SETUP(s2, w2h, w2l, HID)

  // K loop, NT = 24, tile t in buffer t&1.
  STAGE(0, 0);
  VMW0; BAR;
  for (int t = 0; t < 23; ++t) {
    STAGE((t & 1) ^ 1, t + 1);
    COMPUTE(t & 1);
    VMW0; BAR;
  }
  COMPUTE(1);                    // tile 23

  // Epilogue: bias + scatter to out[t][b][o2][p] (channels-first).
#pragma unroll
  for (int n = 0; n < 2; ++n) {
    int colg = n0 + wn * 32 + n * 16 + (lane & 15);
    float bias = b2[colg];
#pragma unroll
    for (int m = 0; m < 4; ++m) {
      int rowbase = m0 + wm * 64 + m * 16 + ((lane >> 4) << 2);
      int pix = rowbase >> 2;       // = b*196 + p   (t = i)
      int bb  = pix / P_;
      int p   = pix - bb * P_;
#pragma unroll
      for (int i = 0; i < 4; ++i) {
        out[(size_t)((i * B_ + bb) * C_ + colg) * P_ + p] = acc[m][n][i] + bias;
      }
    }
  }
}

// ---------------- launcher ----------------
extern "C" void kernel_launch(void* const* d_in, const int* in_sizes, int n_in,
                              void* d_out, int out_size, void* d_ws, size_t ws_size,
                              hipStream_t stream) {
  const float* x   = (const float*)d_in[0];
  const float* pw1 = (const float*)d_in[1];
  const float* w1  = (const float*)d_in[2];
  const float* b1  = (const float*)d_in[3];
  const float* pw2 = (const float*)d_in[4];
  const float* w2  = (const float*)d_in[5];
  const float* b2  = (const float*)d_in[6];
  float* out = (float*)d_out;

  char* ws = (char*)d_ws;
  unsigned short* s1t = (unsigned short*)(ws);
  unsigned short* s2  = (unsigned short*)(ws + 19267584);
  unsigned short* w1h = (unsigned short*)(ws + 19267584 + 77070336);
  unsigned short* w1l = w1h + 589824;
  unsigned short* w2h = w1l + 589824;
  unsigned short* w2l = w2h + 589824;
  (void)in_sizes; (void)n_in; (void)out_size; (void)ws_size;

  prep_w<<<(C_ * HID + 255) / 256, 256, 0, stream>>>(w1, w2, w1h, w1l, w2h, w2l);
  plif1_t<<<dim3(B_, C_ / 64, 4), 256, 0, stream>>>(x, pw1, s1t);
  gemm1_plif2<<<dim3((MTOT / 128) * (HID / 64)), 256, 0, stream>>>(s1t, w1h, w1l, b1, pw2, s2);
  gemm2_out<<<dim3((MTOT / 128) * (C_ / 64)), 256, 0, stream>>>(s2, w2h, w2l, b2, out);
}

// Round 7
// 148.197 us; speedup vs baseline: 1.8103x; 1.2953x over previous
//
#include <hip/hip_runtime.h>
#include <hip/hip_bf16.h>
#include <cstdint>

// Problem constants
#define T_   4
#define B_   32
#define C_   384
#define HID  1536
#define P_   196          // 14*14
#define MTOT 25088        // T_*B_*P_

using f32x4  = __attribute__((ext_vector_type(4))) float;
using bf16x8 = __attribute__((ext_vector_type(8))) __bf16;

static __device__ __forceinline__ unsigned short f32_to_bf16(float f) {
  unsigned int u = __builtin_bit_cast(unsigned int, f);
  unsigned int r = (u + 0x7FFFu + ((u >> 16) & 1u)) >> 16;  // RNE
  return (unsigned short)r;
}
static __device__ __forceinline__ float bf16_to_f32(unsigned short h) {
  return __builtin_bit_cast(float, ((unsigned int)h) << 16);
}

static __device__ __forceinline__ f32x4 mfma16x16x32(bf16x8 a, bf16x8 b, f32x4 c) {
  return __builtin_amdgcn_mfma_f32_16x16x32_bf16(a, b, c, 0, 0, 0);
}

#define GLDS(src, dst)                                                              \
  __builtin_amdgcn_global_load_lds((const __attribute__((address_space(1))) void*)(src), \
                                   (__attribute__((address_space(3))) void*)(dst), 16, 0, 0)

// ---------------- prep: split w1 into bf16 hi+lo; w2 hi only ----------------
// w2_lo dropped: gemm2 output is un-thresholded; residual error ~5e-4 rms << 2e-2 threshold.
__global__ __launch_bounds__(256) void prep_w(const float* __restrict__ w1, const float* __restrict__ w2,
                                              unsigned short* __restrict__ w1h, unsigned short* __restrict__ w1l,
                                              unsigned short* __restrict__ w2h) {
  int i = blockIdx.x * 256 + threadIdx.x;
  if (i >= C_ * HID) return;
  float a = w1[i];
  unsigned short h = f32_to_bf16(a);
  w1h[i] = h;
  w1l[i] = f32_to_bf16(a - bf16_to_f32(h));
  w2h[i] = f32_to_bf16(w2[i]);
}

// ---------------- PLIF on x + transpose to s1t[(b*196+p)*4 + t][c] (bf16 spikes) ----------------
__global__ __launch_bounds__(256) void plif1_t(const float* __restrict__ x, const float* __restrict__ pw1,
                                               unsigned short* __restrict__ s1t) {
  __shared__ float xt[64][65];  // +1 pad: conflict-free transpose
  int b = blockIdx.x, c0 = blockIdx.y * 64, p0 = blockIdx.z * 64;
  int tid  = threadIdx.x;
  int c    = tid & 63;
  int prow = tid >> 6;
  float d1 = 1.0f / (1.0f + expf(-pw1[0]));
  float v[16];
#pragma unroll
  for (int k = 0; k < 16; ++k) v[k] = 0.0f;

  for (int t = 0; t < 4; ++t) {
    __syncthreads();
#pragma unroll
    for (int i = 0; i < 16; ++i) {
      int l = tid + i * 256;
      int cl = l >> 6, pl = l & 63;
      if (p0 + pl < P_)
        xt[cl][pl] = x[(size_t)((t * B_ + b) * C_ + c0 + cl) * P_ + p0 + pl];
    }
    __syncthreads();
#pragma unroll
    for (int k = 0; k < 16; ++k) {
      int p = prow + 4 * k;  // 0..63
      if (p0 + p < P_) {
        float xv = xt[c][p];
        float H  = v[k] + (xv - v[k]) * d1;        // same expr as reference
        bool  s  = (H - 1.0f) >= 0.0f;             // ATan surrogate fwd = heaviside
        s1t[(size_t)((b * P_ + p0 + p) * 4 + t) * C_ + c0 + c] = s ? (unsigned short)0x3F80 : (unsigned short)0;
        v[k] = s ? 0.0f : H;                        // hard reset to 0
      }
    }
  }
}

// ---------------- GEMM1 (s1t[M,K=384] x w1[N=1536,K]) fused with PLIF2 -> s2 spikes bf16 ----------------
// R2-proven structure: plain 2-barrier loop, BM=128 BN=128 BK=64, 72KB LDS, grid 2352 (8*294 swizzle).
__global__ __launch_bounds__(256) void gemm1_plif2(const unsigned short* __restrict__ s1t,
                                                   const unsigned short* __restrict__ w1h,
                                                   const unsigned short* __restrict__ w1l,
                                                   const float* __restrict__ b1, const float* __restrict__ pw2,
                                                   unsigned short* __restrict__ s2) {
  __shared__ unsigned short As[128 * 64];
  __shared__ unsigned short Bh[128 * 64];
  __shared__ unsigned short Bl[128 * 64];
  int tid = threadIdx.x;
  int lane = tid & 63, wave = tid >> 6;
  int wm = wave >> 1, wn = wave & 1;
  // XCD-chunked bijective swizzle: all 12 N-tiles of an A-panel land in one XCD's L2.
  int gid = blockIdx.x;          // 0..2351
  int xcd = gid & 7, pos = gid >> 3;
  int lin = xcd * 294 + pos;
  int bx = lin / 12, by = lin - bx * 12;
  int m0 = bx * 128, n0 = by * 128;

  f32x4 acc[4][4];
#pragma unroll
  for (int m = 0; m < 4; ++m)
#pragma unroll
    for (int n = 0; n < 4; ++n) acc[m][n] = (f32x4)0.0f;

  for (int kt = 0; kt < C_ / 64; ++kt) {
    int k0 = kt * 64;
#pragma unroll
    for (int i = 0; i < 4; ++i) {
      int l = i * 256 + tid;
      int row = l >> 3;
      int kblk = (l & 7) ^ (row & 7);  // pre-swizzled source so linear LDS + swizzled read match
      const unsigned short* sA = s1t + (size_t)(m0 + row) * C_ + k0 + kblk * 8;
      const unsigned short* sH = w1h + (size_t)(n0 + row) * C_ + k0 + kblk * 8;
      const unsigned short* sL = w1l + (size_t)(n0 + row) * C_ + k0 + kblk * 8;
      unsigned short* dA = As + i * 2048 + wave * 512;  // wave-uniform base; HW adds lane*16B
      unsigned short* dH = Bh + i * 2048 + wave * 512;
      unsigned short* dL = Bl + i * 2048 + wave * 512;
      GLDS(sA, dA);
      GLDS(sH, dH);
      GLDS(sL, dL);
    }
    __syncthreads();
#pragma unroll
    for (int ks = 0; ks < 2; ++ks) {
      bf16x8 a[4], bh[4], bl[4];
      int kof = ks * 32 + ((lane >> 4) << 3);
#pragma unroll
      for (int m = 0; m < 4; ++m) {
        int row = wm * 64 + m * 16 + (lane & 15);
        a[m] = *(const bf16x8*)&As[row * 64 + (kof ^ ((row & 7) << 3))];
      }
#pragma unroll
      for (int n = 0; n < 4; ++n) {
        int row = wn * 64 + n * 16 + (lane & 15);
        int idx = row * 64 + (kof ^ ((row & 7) << 3));
        bh[n] = *(const bf16x8*)&Bh[idx];
        bl[n] = *(const bf16x8*)&Bl[idx];
      }
#pragma unroll
      for (int m = 0; m < 4; ++m)
#pragma unroll
        for (int n = 0; n < 4; ++n) {
          acc[m][n] = mfma16x16x32(a[m], bh[n], acc[m][n]);
          acc[m][n] = mfma16x16x32(a[m], bl[n], acc[m][n]);
        }
    }
    __syncthreads();
  }

  // Epilogue: rows are (pixel*4 + t); each lane's 4 acc regs = t=0..3 of one pixel -> PLIF2 in registers.
  float d2 = 1.0f / (1.0f + expf(-pw2[0]));
#pragma unroll
  for (int n = 0; n < 4; ++n) {
    int colg = n0 + wn * 64 + n * 16 + (lane & 15);
    float bias = b1[colg];
#pragma unroll
    for (int m = 0; m < 4; ++m) {
      int rowbase = m0 + wm * 64 + m * 16 + ((lane >> 4) << 2);
      float v = 0.0f;
#pragma unroll
      for (int i = 0; i < 4; ++i) {  // i == t
        float xv = acc[m][n][i] + bias;
        float H  = v + (xv - v) * d2;
        bool  s  = (H - 1.0f) >= 0.0f;
        s2[(size_t)(rowbase + i) * HID + colg] = s ? (unsigned short)0x3F80 : (unsigned short)0;
        v = s ? 0.0f : H;
      }
    }
  }
}

// ---------------- GEMM2 (s2[M,K=1536] x w2h[N=384,K]) + bias, scatter to channels-first out ----------------
// R2-proven structure, hi-only B: BM=128 BN=64 BK=64, LDS 24KB -> ~6 blocks/CU. Grid 1176 (8*147 swizzle).
__global__ __launch_bounds__(256) void gemm2_out(const unsigned short* __restrict__ s2,
                                                 const unsigned short* __restrict__ w2h,
                                                 const float* __restrict__ b2, float* __restrict__ out) {
  __shared__ unsigned short As[128 * 64];
  __shared__ unsigned short Bh[64 * 64];
  int tid = threadIdx.x;
  int lane = tid & 63, wave = tid >> 6;
  int wm = wave >> 1, wn = wave & 1;  // wm: 2x64 rows, wn: 2x32 cols
  // XCD-chunked bijective swizzle: all 6 N-tiles of an A-panel land in one XCD's L2.
  int gid = blockIdx.x;          // 0..1175
  int xcd = gid & 7, pos = gid >> 3;
  int lin = xcd * 147 + pos;
  int bx = lin / 6, by = lin - bx * 6;
  int m0 = bx * 128, n0 = by * 64;

  f32x4 acc[4][2];
#pragma unroll
  for (int m = 0; m < 4; ++m)
#pragma unroll
    for (int n = 0; n < 2; ++n) acc[m][n] = (f32x4)0.0f;

  for (int kt = 0; kt < HID / 64; ++kt) {
    int k0 = kt * 64;
#pragma unroll
    for (int i = 0; i < 4; ++i) {  // A: 128 rows
      int l = i * 256 + tid;
      int row = l >> 3;
      int kblk = (l & 7) ^ (row & 7);
      const unsigned short* sA = s2 + (size_t)(m0 + row) * HID + k0 + kblk * 8;
      GLDS(sA, As + i * 2048 + wave * 512);
    }
#pragma unroll
    for (int i = 0; i < 2; ++i) {  // B: 64 rows, hi only
      int l = i * 256 + tid;
      int row = l >> 3;
      int kblk = (l & 7) ^ (row & 7);
      const unsigned short* sH = w2h + (size_t)(n0 + row) * HID + k0 + kblk * 8;
      GLDS(sH, Bh + i * 2048 + wave * 512);
    }
    __syncthreads();
#pragma unroll
    for (int ks = 0; ks < 2; ++ks) {
      bf16x8 a[4], bh[2];
      int kof = ks * 32 + ((lane >> 4) << 3);
#pragma unroll
      for (int m = 0; m < 4; ++m) {
        int row = wm * 64 + m * 16 + (lane & 15);
        a[m] = *(const bf16x8*)&As[row * 64 + (kof ^ ((row & 7) << 3))];
      }
#pragma unroll
      for (int n = 0; n < 2; ++n) {
        int row = wn * 32 + n * 16 + (lane & 15);
        int idx = row * 64 + (kof ^ ((row & 7) << 3));
        bh[n] = *(const bf16x8*)&Bh[idx];
      }
#pragma unroll
      for (int m = 0; m < 4; ++m)
#pragma unroll
        for (int n = 0; n < 2; ++n)
          acc[m][n] = mfma16x16x32(a[m], bh[n], acc[m][n]);
    }
    __syncthreads();
  }

  // Epilogue: bias + scatter to out[t][b][o2][p] (channels-first).
#pragma unroll
  for (int n = 0; n < 2; ++n) {
    int colg = n0 + wn * 32 + n * 16 + (lane & 15);
    float bias = b2[colg];
#pragma unroll
    for (int m = 0; m < 4; ++m) {
      int rowbase = m0 + wm * 64 + m * 16 + ((lane >> 4) << 2);
      int pix = rowbase >> 2;       // = b*196 + p   (t = i)
      int bb  = pix / P_;
      int p   = pix - bb * P_;
#pragma unroll
      for (int i = 0; i < 4; ++i) {
        out[(size_t)((i * B_ + bb) * C_ + colg) * P_ + p] = acc[m][n][i] + bias;
      }
    }
  }
}

// ---------------- launcher ----------------
extern "C" void kernel_launch(void* const* d_in, const int* in_sizes, int n_in,
                              void* d_out, int out_size, void* d_ws, size_t ws_size,
                              hipStream_t stream) {
  const float* x   = (const float*)d_in[0];
  const float* pw1 = (const float*)d_in[1];
  const float* w1  = (const float*)d_in[2];
  const float* b1  = (const float*)d_in[3];
  const float* pw2 = (const float*)d_in[4];
  const float* w2  = (const float*)d_in[5];
  const float* b2  = (const float*)d_in[6];
  float* out = (float*)d_out;

  char* ws = (char*)d_ws;
  unsigned short* s1t = (unsigned short*)(ws);
  unsigned short* s2  = (unsigned short*)(ws + 19267584);
  unsigned short* w1h = (unsigned short*)(ws + 19267584 + 77070336);
  unsigned short* w1l = w1h + 589824;
  unsigned short* w2h = w1l + 589824;
  (void)in_sizes; (void)n_in; (void)out_size; (void)ws_size;

  prep_w<<<(C_ * HID + 255) / 256, 256, 0, stream>>>(w1, w2, w1h, w1l, w2h);
  plif1_t<<<dim3(B_, C_ / 64, 4), 256, 0, stream>>>(x, pw1, s1t);
  gemm1_plif2<<<dim3(MTOT / 128 * (HID / 128)), 256, 0, stream>>>(s1t, w1h, w1l, b1, pw2, s2);
  gemm2_out<<<dim3(MTOT / 128 * (C_ / 64)), 256, 0, stream>>>(s2, w2h, b2, out);
}